// Round 3
// baseline (4566.840 us; speedup 1.0000x reference)
//
#include <hip/hip_runtime.h>
#include <hip/hip_bf16.h>

#define TT 256
#define BB 128
#define EMBD 256
#define HID 512
#define KTAG 12
#define START_TAG 10
#define STOP_TAG 11
#define GBLK 32           // blocks per recurrence group
#define SMEM_BYTES 156160 // 96KB W + 48KB A + 8.5KB gl

typedef __attribute__((ext_vector_type(8))) short short8;
typedef __attribute__((ext_vector_type(4))) float f32x4;

__device__ __forceinline__ float sigm(float x) { return 1.0f / (1.0f + expf(-x)); }

__device__ __forceinline__ unsigned short f2bf(float f) {
    union { float f; unsigned int u; } v; v.f = f;
    unsigned int r = v.u + 0x7fffu + ((v.u >> 16) & 1u);   // RNE
    return (unsigned short)(r >> 16);
}

__device__ __forceinline__ void gll16(const void* g, void* l) {
    __builtin_amdgcn_global_load_lds((const __attribute__((address_space(1))) void*)g,
                                     (__attribute__((address_space(3))) void*)l, 16, 0, 0);
}

// ---------------- prologue: h0->bf16, bias sums, barrier zero ----------------
__global__ void prep_state(const float* __restrict__ h0,
                           const float* __restrict__ bihf, const float* __restrict__ bhhf,
                           const float* __restrict__ bihb, const float* __restrict__ bhhb,
                           unsigned short* __restrict__ h0buf, float* __restrict__ bias2,
                           unsigned int* __restrict__ bar)
{
    int i = blockIdx.x * blockDim.x + threadIdx.x;
    if (i < 2 * BB * HID) h0buf[i] = f2bf(h0[i]);
    if (i < 2 * 2048) {
        int dir = i >> 11, j = i & 2047;
        bias2[i] = dir ? (bihb[j] + bhhb[j]) : (bihf[j] + bhhf[j]);
    }
    if (i < 8 * 64) bar[i] = 0u;
}

// ---------------- prologue: gather embeddings -> bf16 xs[T][B][EMBD] ----------------
__global__ void xs_gather(const int* __restrict__ x, const float* __restrict__ emb,
                          unsigned short* __restrict__ xs)
{
    int i = blockIdx.x * blockDim.x + threadIdx.x;
    if (i >= TT * BB * (EMBD / 8)) return;
    int chk = i & 31;
    int row = i >> 5;            // t*BB + b
    int b = row & (BB - 1);
    int t = row >> 7;
    const float* src = emb + (size_t)x[b * TT + t] * EMBD + chk * 8;
    float4 v0 = *(const float4*)(src);
    float4 v1 = *(const float4*)(src + 4);
    unsigned short tmp[8];
    tmp[0] = f2bf(v0.x); tmp[1] = f2bf(v0.y); tmp[2] = f2bf(v0.z); tmp[3] = f2bf(v0.w);
    tmp[4] = f2bf(v1.x); tmp[5] = f2bf(v1.y); tmp[6] = f2bf(v1.z); tmp[7] = f2bf(v1.w);
    *(uint4*)(xs + (size_t)row * EMBD + chk * 8) = *(const uint4*)tmp;
}

// ---------------- prologue: reorder weights -> bf16 Wr[2][2048][768] ----------------
// new row nr = utile*64 + g*16 + uu  <->  original row g*512 + utile*16 + uu
__global__ void w_reorder(const float* __restrict__ Wihf, const float* __restrict__ Whhf,
                          const float* __restrict__ Wihb, const float* __restrict__ Whhb,
                          unsigned short* __restrict__ Wr)
{
    int i = blockIdx.x * blockDim.x + threadIdx.x;
    if (i >= 2 * 2048 * (768 / 8)) return;
    int c8 = i % 96;
    int r2 = i / 96;
    int nr = r2 & 2047;
    int dir = r2 >> 11;
    int utile = nr >> 6;
    int g = (nr >> 4) & 3;
    int uu = nr & 15;
    int orow = g * HID + utile * 16 + uu;
    int k0 = c8 * 8;
    const float* Wih = dir ? Wihb : Wihf;
    const float* Whh = dir ? Whhb : Whhf;
    const float* src = (k0 < EMBD) ? (Wih + (size_t)orow * EMBD + k0)
                                   : (Whh + (size_t)orow * HID + (k0 - EMBD));
    float4 v0 = *(const float4*)(src);
    float4 v1 = *(const float4*)(src + 4);
    unsigned short tmp[8];
    tmp[0] = f2bf(v0.x); tmp[1] = f2bf(v0.y); tmp[2] = f2bf(v0.z); tmp[3] = f2bf(v0.w);
    tmp[4] = f2bf(v1.x); tmp[5] = f2bf(v1.y); tmp[6] = f2bf(v1.z); tmp[7] = f2bf(v1.w);
    *(uint4*)(Wr + ((size_t)dir * 2048 + nr) * 768 + k0) = *(const uint4*)tmp;
}

// ---------------- persistent BiLSTM: all 256 timesteps in one kernel ----------------
// 256 blocks x 256 threads. blk: grp = blk&7 (dir = grp>>2, btile = grp&3), utile = blk>>3.
// Group of 32 blocks (same dir,btile) owns batch slab [32b x 512u] recurrence; epoch barrier per group.
// LDS: Wlds[4n][24ks][512] resident, Abuf[2m][24ks][512] per step, gl[32][68] f32 scratch.
__launch_bounds__(256, 1)
__global__ void lstm_persistent(
    const unsigned short* __restrict__ xs, const unsigned short* __restrict__ Wr,
    const float* __restrict__ bias2, const int* __restrict__ lengths,
    const unsigned short* __restrict__ h0buf, const float* __restrict__ c0,
    unsigned short* __restrict__ hsf, unsigned short* __restrict__ hsb,
    unsigned int* __restrict__ bar)
{
    extern __shared__ char smem[];
    unsigned short* Wlds = (unsigned short*)smem;                     // 98304 B
    unsigned short* Abuf = (unsigned short*)(smem + 98304);           // 49152 B
    float* gl = (float*)(smem + 98304 + 49152);                       // 8704 B

    const int blk = blockIdx.x;
    const int grp = blk & 7;
    const int dir = grp >> 2;
    const int btile = grp & 3;
    const int utile = blk >> 3;
    const int bg0 = btile * 32;

    const int tid = threadIdx.x;
    const int w = tid >> 6;
    const int l = tid & 63;
    const int l15 = l & 15, l16 = l >> 4;

    unsigned int* bcnt  = bar + grp * 64;
    unsigned int* bflag = bar + grp * 64 + 16;

    const unsigned short* Wb = Wr + ((size_t)(dir * 2048 + utile * 64)) * 768;
    unsigned short* hs = dir ? hsb : hsf;

    // ---- stage resident W: wave w stages n-subtile w (24 k-subtiles)
    {
        const unsigned short* src0 = Wb + (size_t)(w * 16 + l15) * 768 + l16 * 8;
        #pragma unroll
        for (int ks = 0; ks < 24; ks++)
            gll16(src0 + ks * 32, Wlds + (w * 24 + ks) * 512);
    }

    // ---- persistent per-thread state (pointwise role: 2 (b,u) pairs)
    const int bl0 = tid >> 4, uu = tid & 15;
    const int u = utile * 16 + uu;
    float c_reg[2]; int len_r[2];
    #pragma unroll
    for (int pp = 0; pp < 2; pp++) {
        int bl = pp * 16 + bl0;
        int b = bg0 + bl;
        c_reg[pp] = c0[((size_t)dir * BB + b) * HID + u];
        len_r[pp] = lengths[b];
    }
    float bias_r[4];
    #pragma unroll
    for (int g = 0; g < 4; g++) bias_r[g] = bias2[dir * 2048 + g * 512 + u];

    const int m  = w & 1;          // this wave's m-subtile
    const int n0 = (w >> 1) * 2;   // this wave's first n-subtile (= gate index)

    __syncthreads();               // W staged (vmcnt drained by barrier)

    for (int s = 0; s < TT; s++) {
        const int t = dir ? (TT - 1 - s) : s;

        // ---- stage xs part (ks 0..7): wave w covers m'=w&1, ks = (w>>1)*4 .. +4
        {
            int mm = w & 1;
            int ksb = (w >> 1) * 4;
            const unsigned short* asrc =
                xs + ((size_t)t * BB + (bg0 + mm * 16 + l15)) * EMBD + l16 * 8;
            #pragma unroll
            for (int q = 0; q < 4; q++)
                gll16(asrc + (ksb + q) * 32, Abuf + (mm * 24 + ksb + q) * 512);
        }
        __syncthreads();

        f32x4 acc0 = {0.f, 0.f, 0.f, 0.f}, acc1 = {0.f, 0.f, 0.f, 0.f};
        #pragma unroll
        for (int ks = 0; ks < 8; ks++) {
            short8 a  = *(const short8*)(Abuf + ((m * 24 + ks) << 9) + (l << 3));
            short8 b0 = *(const short8*)(Wlds + ((n0 * 24 + ks) << 9) + (l << 3));
            short8 b1 = *(const short8*)(Wlds + (((n0 + 1) * 24 + ks) << 9) + (l << 3));
            acc0 = __builtin_amdgcn_mfma_f32_16x16x32_bf16(a, b0, acc0, 0, 0, 0);
            acc1 = __builtin_amdgcn_mfma_f32_16x16x32_bf16(a, b1, acc1, 0, 0, 0);
        }

        // ---- wait for h(t prev) from the group (epoch barrier)
        if (s > 0) {
            if (tid == 0) {
                while (__hip_atomic_load(bflag, __ATOMIC_RELAXED, __HIP_MEMORY_SCOPE_AGENT)
                       < (unsigned)s)
                    __builtin_amdgcn_s_sleep(1);
                __threadfence();   // acquire: invalidate stale caches
            }
            __syncthreads();
        }
        const unsigned short* hsrc = (s == 0)
            ? (h0buf + (size_t)dir * BB * HID)
            : (hs + (size_t)(dir ? (t + 1) : (t - 1)) * BB * HID);

        // ---- stage h part (ks 8..23): wave w covers m'=w&1, ks = 8+(w>>1)*8 .. +8
        {
            int mm = w & 1;
            int ksb = 8 + (w >> 1) * 8;
            const unsigned short* asrcH = hsrc + (size_t)(bg0 + mm * 16 + l15) * HID + l16 * 8;
            #pragma unroll
            for (int q = 0; q < 8; q++) {
                int ks = ksb + q;
                gll16(asrcH + (ks * 32 - 256), Abuf + (mm * 24 + ks) * 512);
            }
        }
        __syncthreads();

        #pragma unroll
        for (int ks = 8; ks < 24; ks++) {
            short8 a  = *(const short8*)(Abuf + ((m * 24 + ks) << 9) + (l << 3));
            short8 b0 = *(const short8*)(Wlds + ((n0 * 24 + ks) << 9) + (l << 3));
            short8 b1 = *(const short8*)(Wlds + (((n0 + 1) * 24 + ks) << 9) + (l << 3));
            acc0 = __builtin_amdgcn_mfma_f32_16x16x32_bf16(a, b0, acc0, 0, 0, 0);
            acc1 = __builtin_amdgcn_mfma_f32_16x16x32_bf16(a, b1, acc1, 0, 0, 0);
        }

        // ---- accumulators -> gl (C layout: col = l&15, row = 4*(l>>4)+r ; verified R2)
        {
            int rb = m * 16 + l16 * 4;
            #pragma unroll
            for (int r = 0; r < 4; r++) {
                gl[(rb + r) * 68 + n0 * 16 + l15]       = acc0[r];
                gl[(rb + r) * 68 + (n0 + 1) * 16 + l15] = acc1[r];
            }
        }
        __syncthreads();

        // ---- pointwise LSTM update (c in registers), store hs[t]
        #pragma unroll
        for (int pp = 0; pp < 2; pp++) {
            int bl = pp * 16 + bl0;
            float gi = gl[bl * 68 +      uu] + bias_r[0];
            float gf = gl[bl * 68 + 16 + uu] + bias_r[1];
            float gg = gl[bl * 68 + 32 + uu] + bias_r[2];
            float go = gl[bl * 68 + 48 + uu] + bias_r[3];
            bool msk = t < len_r[pp];
            unsigned short hv;
            if (msk) {
                float cn = sigm(gf) * c_reg[pp] + sigm(gi) * tanhf(gg);
                c_reg[pp] = cn;
                hv = f2bf(sigm(go) * tanhf(cn));
            } else {
                // carried h: read h_prev back out of Abuf fragment layout (k = 256+u)
                int k = 256 + u;
                int ks = k >> 5, kin = k & 31;
                hv = Abuf[((bl >> 4) * 24 + ks) * 512 + ((kin >> 3) * 16 + (bl & 15)) * 8 + (kin & 7)];
            }
            hs[((size_t)t * BB + (bg0 + bl)) * HID + u] = hv;
        }
        __syncthreads();           // drains hs stores (vmcnt before s_barrier)

        // ---- arrive
        if (tid == 0) {
            __threadfence();       // release: publish hs stores device-wide
            unsigned a = __hip_atomic_fetch_add(bcnt, 1u, __ATOMIC_ACQ_REL,
                                                __HIP_MEMORY_SCOPE_AGENT);
            if (a == GBLK - 1u) {
                __hip_atomic_store(bcnt, 0u, __ATOMIC_RELAXED, __HIP_MEMORY_SCOPE_AGENT);
                __hip_atomic_store(bflag, (unsigned)(s + 1), __ATOMIC_RELEASE,
                                   __HIP_MEMORY_SCOPE_AGENT);
            }
        }
    }
}

// ---------------- emissions: one wave per (t,b) row ----------------
__global__ void emissions_wave(const unsigned short* __restrict__ hsf,
                               const unsigned short* __restrict__ hsb,
                               const float* __restrict__ fcW, const float* __restrict__ fcb,
                               float* __restrict__ emis)
{
    int wid = (blockIdx.x * blockDim.x + threadIdx.x) >> 6;
    int l = threadIdx.x & 63;
    if (wid >= TT * BB) return;
    uint4 vf = *(const uint4*)(hsf + (size_t)wid * HID + l * 8);
    uint4 vb = *(const uint4*)(hsb + (size_t)wid * HID + l * 8);
    unsigned int uf[4] = {vf.x, vf.y, vf.z, vf.w};
    unsigned int ub[4] = {vb.x, vb.y, vb.z, vb.w};
    float xf[8], xb[8];
    #pragma unroll
    for (int j = 0; j < 4; j++) {
        xf[2*j]   = __uint_as_float(uf[j] << 16);
        xf[2*j+1] = __uint_as_float(uf[j] & 0xffff0000u);
        xb[2*j]   = __uint_as_float(ub[j] << 16);
        xb[2*j+1] = __uint_as_float(ub[j] & 0xffff0000u);
    }
    float acc[KTAG];
    #pragma unroll
    for (int k = 0; k < KTAG; k++) {
        const float* wfp = fcW + k * 1024 + l * 8;
        const float* wbp = fcW + k * 1024 + 512 + l * 8;
        float a = 0.f;
        #pragma unroll
        for (int j = 0; j < 8; j++) a += xf[j] * wfp[j] + xb[j] * wbp[j];
        acc[k] = a;
    }
    #pragma unroll
    for (int k = 0; k < KTAG; k++) {
        #pragma unroll
        for (int off = 32; off >= 1; off >>= 1) acc[k] += __shfl_xor(acc[k], off, 64);
    }
    if (l == 0) {
        float* e = emis + (size_t)wid * KTAG;
        #pragma unroll
        for (int k = 0; k < KTAG; k++) e[k] = acc[k] + fcb[k];
    }
}

// ---------------- CRF log-partition: one wave per batch row ----------------
__global__ void crf_partition_kernel(const float* __restrict__ emis, const int* __restrict__ lengths,
                                     const float* __restrict__ trans, float* __restrict__ logz)
{
    int b = blockIdx.x;
    int lane = threadIdx.x;   // 64
    float trow[KTAG];
    #pragma unroll
    for (int j = 0; j < KTAG; j++)
        trow[j] = (lane < KTAG) ? trans[lane * KTAG + j] : -1e30f;
    float alpha = (lane == START_TAG) ? 0.0f : -10000.0f;
    int len = lengths[b];
    for (int t = 0; t < len; t++) {
        float sc[KTAG];
        #pragma unroll
        for (int j = 0; j < KTAG; j++) {
            float aj = __shfl(alpha, j, 64);
            sc[j] = aj + trow[j];
        }
        float m = sc[0];
        #pragma unroll
        for (int j = 1; j < KTAG; j++) m = fmaxf(m, sc[j]);
        float ssum = 0.0f;
        #pragma unroll
        for (int j = 0; j < KTAG; j++) ssum += expf(sc[j] - m);
        float em = (lane < KTAG) ? emis[((size_t)t * BB + b) * KTAG + lane] : 0.0f;
        float anew = m + logf(ssum) + em;
        alpha = (lane < KTAG) ? anew : alpha;
    }
    float v = (lane < KTAG) ? (alpha + trans[STOP_TAG * KTAG + lane]) : -1e30f;
    float m = v;
    #pragma unroll
    for (int off = 1; off < 16; off <<= 1) m = fmaxf(m, __shfl_xor(m, off, 64));
    float e = expf(v - m);
    #pragma unroll
    for (int off = 1; off < 16; off <<= 1) e += __shfl_xor(e, off, 64);
    if (lane == 0) logz[b] = m + logf(e);
}

// ---------------- gold score + final output ----------------
__global__ void gold_kernel(const float* __restrict__ emis, const int* __restrict__ tags,
                            const int* __restrict__ lengths, const float* __restrict__ trans,
                            const float* __restrict__ logz, float* __restrict__ out)
{
    int b = blockIdx.x * blockDim.x + threadIdx.x;
    if (b >= BB) return;
    int len = lengths[b];
    float score = 0.0f;
    int prev = START_TAG;
    for (int t = 0; t < len; t++) {
        int nxt = tags[b * TT + t];
        score += trans[nxt * KTAG + prev] + emis[((size_t)t * BB + b) * KTAG + nxt];
        prev = nxt;
    }
    score += trans[STOP_TAG * KTAG + prev];
    out[b] = logz[b] - score;
}

extern "C" void kernel_launch(void* const* d_in, const int* in_sizes, int n_in,
                              void* d_out, int out_size, void* d_ws, size_t ws_size,
                              hipStream_t stream)
{
    (void)in_sizes; (void)n_in; (void)out_size; (void)ws_size;
    const int*   x     = (const int*)d_in[0];
    const int*   lens  = (const int*)d_in[1];
    const int*   tags  = (const int*)d_in[2];
    const float* emb   = (const float*)d_in[3];
    const float* Wihf  = (const float*)d_in[4];
    const float* Whhf  = (const float*)d_in[5];
    const float* bihf  = (const float*)d_in[6];
    const float* bhhf  = (const float*)d_in[7];
    const float* Wihb  = (const float*)d_in[8];
    const float* Whhb  = (const float*)d_in[9];
    const float* bihb  = (const float*)d_in[10];
    const float* bhhb  = (const float*)d_in[11];
    const float* fcW   = (const float*)d_in[12];
    const float* fcb   = (const float*)d_in[13];
    const float* trans = (const float*)d_in[14];
    const float* h0    = (const float*)d_in[15];
    const float* c0    = (const float*)d_in[16];
    float* out = (float*)d_out;

    char* ws = (char*)d_ws;
    size_t off = 0;
    auto alloc = [&](size_t bytes) {
        void* p = ws + off;
        off += (bytes + 255) & ~(size_t)255;
        return p;
    };
    unsigned short* xs    = (unsigned short*)alloc((size_t)TT * BB * EMBD * 2);
    unsigned short* Wr    = (unsigned short*)alloc((size_t)2 * 2048 * 768 * 2);
    float*          bias2 = (float*)alloc((size_t)2 * 2048 * 4);
    unsigned short* h0buf = (unsigned short*)alloc((size_t)2 * BB * HID * 2);
    unsigned short* hsf   = (unsigned short*)alloc((size_t)TT * BB * HID * 2);
    unsigned short* hsb   = (unsigned short*)alloc((size_t)TT * BB * HID * 2);
    float*          emis  = (float*)alloc((size_t)TT * BB * KTAG * 4);
    float*          logz  = (float*)alloc((size_t)BB * 4);
    unsigned int*   bar   = (unsigned int*)alloc((size_t)8 * 64 * 4);

    prep_state<<<512, 256, 0, stream>>>(h0, bihf, bhhf, bihb, bhhb, h0buf, bias2, bar);
    xs_gather<<<4096, 256, 0, stream>>>(x, emb, xs);
    w_reorder<<<1536, 256, 0, stream>>>(Wihf, Whhf, Wihb, Whhb, Wr);

    hipFuncSetAttribute(reinterpret_cast<const void*>(lstm_persistent),
                        hipFuncAttributeMaxDynamicSharedMemorySize, SMEM_BYTES);
    {
        const unsigned short* p_xs = xs; const unsigned short* p_Wr = Wr;
        const float* p_bias2 = bias2; const int* p_lens = lens;
        const unsigned short* p_h0 = h0buf; const float* p_c0 = c0;
        unsigned short* p_hsf = hsf; unsigned short* p_hsb = hsb;
        unsigned int* p_bar = bar;
        void* args[9] = { &p_xs, &p_Wr, &p_bias2, &p_lens, &p_h0, &p_c0,
                          &p_hsf, &p_hsb, &p_bar };
        hipError_t e = hipLaunchCooperativeKernel(
            reinterpret_cast<const void*>(lstm_persistent),
            dim3(256), dim3(256), args, (unsigned)SMEM_BYTES, stream);
        if (e != hipSuccess) {
            // fallback: grid == CU count at 1 block/CU -> co-resident in practice
            lstm_persistent<<<256, 256, SMEM_BYTES, stream>>>(
                xs, Wr, bias2, lens, h0buf, c0, hsf, hsb, bar);
        }
    }

    emissions_wave<<<8192, 256, 0, stream>>>(hsf, hsb, fcW, fcb, emis);
    crf_partition_kernel<<<BB, 64, 0, stream>>>(emis, lens, trans, logz);
    gold_kernel<<<1, BB, 0, stream>>>(emis, tags, lens, trans, logz, out);
}

// Round 5
// 1443.908 us; speedup vs baseline: 3.1628x; 3.1628x over previous
//
#include <hip/hip_runtime.h>
#include <hip/hip_bf16.h>

#define TT 256
#define BB 128
#define EMBD 256
#define HID 512
#define KTAG 12
#define START_TAG 10
#define STOP_TAG 11
#define GBLK 32u
#define SMEM_BYTES 156160 // 96KB W + 48KB A + 8.5KB gl

typedef __attribute__((ext_vector_type(8))) short short8;
typedef __attribute__((ext_vector_type(4))) float f32x4;

__device__ __forceinline__ float sigm(float x) { return 1.0f / (1.0f + expf(-x)); }

__device__ __forceinline__ unsigned short f2bf(float f) {
    union { float f; unsigned int u; } v; v.f = f;
    unsigned int r = v.u + 0x7fffu + ((v.u >> 16) & 1u);   // RNE
    return (unsigned short)(r >> 16);
}

__device__ __forceinline__ void gll16(const void* g, void* l) {
    __builtin_amdgcn_global_load_lds((const __attribute__((address_space(1))) void*)g,
                                     (__attribute__((address_space(3))) void*)l, 16, 0, 0);
}

// ---------------- prologue: h0->bf16, bias sums, ctrl zero ----------------
__global__ void prep_state(const float* __restrict__ h0,
                           const float* __restrict__ bihf, const float* __restrict__ bhhf,
                           const float* __restrict__ bihb, const float* __restrict__ bhhb,
                           unsigned short* __restrict__ h0buf, float* __restrict__ bias2,
                           unsigned int* __restrict__ ctrl)
{
    int i = blockIdx.x * blockDim.x + threadIdx.x;
    if (i < 2 * BB * HID) h0buf[i] = f2bf(h0[i]);
    if (i < 2 * 2048) {
        int dir = i >> 11, j = i & 2047;
        bias2[i] = dir ? (bihb[j] + bhhb[j]) : (bihf[j] + bhhf[j]);
    }
    if (i < 512) ctrl[i] = 0u;
}

// ---------------- prologue: gather embeddings -> bf16 xs[T][B][EMBD] ----------------
__global__ void xs_gather(const int* __restrict__ x, const float* __restrict__ emb,
                          unsigned short* __restrict__ xs)
{
    int i = blockIdx.x * blockDim.x + threadIdx.x;
    if (i >= TT * BB * (EMBD / 8)) return;
    int chk = i & 31;
    int row = i >> 5;            // t*BB + b
    int b = row & (BB - 1);
    int t = row >> 7;
    const float* src = emb + (size_t)x[b * TT + t] * EMBD + chk * 8;
    float4 v0 = *(const float4*)(src);
    float4 v1 = *(const float4*)(src + 4);
    unsigned short tmp[8];
    tmp[0] = f2bf(v0.x); tmp[1] = f2bf(v0.y); tmp[2] = f2bf(v0.z); tmp[3] = f2bf(v0.w);
    tmp[4] = f2bf(v1.x); tmp[5] = f2bf(v1.y); tmp[6] = f2bf(v1.z); tmp[7] = f2bf(v1.w);
    *(uint4*)(xs + (size_t)row * EMBD + chk * 8) = *(const uint4*)tmp;
}

// ---------------- prologue: reorder weights -> bf16 Wr[2][2048][768] ----------------
// new row nr = utile*64 + g*16 + uu  <->  original row g*512 + utile*16 + uu
__global__ void w_reorder(const float* __restrict__ Wihf, const float* __restrict__ Whhf,
                          const float* __restrict__ Wihb, const float* __restrict__ Whhb,
                          unsigned short* __restrict__ Wr)
{
    int i = blockIdx.x * blockDim.x + threadIdx.x;
    if (i >= 2 * 2048 * (768 / 8)) return;
    int c8 = i % 96;
    int r2 = i / 96;
    int nr = r2 & 2047;
    int dir = r2 >> 11;
    int utile = nr >> 6;
    int g = (nr >> 4) & 3;
    int uu = nr & 15;
    int orow = g * HID + utile * 16 + uu;
    int k0 = c8 * 8;
    const float* Wih = dir ? Wihb : Wihf;
    const float* Whh = dir ? Whhb : Whhf;
    const float* src = (k0 < EMBD) ? (Wih + (size_t)orow * EMBD + k0)
                                   : (Whh + (size_t)orow * HID + (k0 - EMBD));
    float4 v0 = *(const float4*)(src);
    float4 v1 = *(const float4*)(src + 4);
    unsigned short tmp[8];
    tmp[0] = f2bf(v0.x); tmp[1] = f2bf(v0.y); tmp[2] = f2bf(v0.z); tmp[3] = f2bf(v0.w);
    tmp[4] = f2bf(v1.x); tmp[5] = f2bf(v1.y); tmp[6] = f2bf(v1.z); tmp[7] = f2bf(v1.w);
    *(uint4*)(Wr + ((size_t)dir * 2048 + nr) * 768 + k0) = *(const uint4*)tmp;
}

// ---------------- persistent BiLSTM: fence-free producer/consumer ----------------
// 256 blocks x 256 threads, 1 block/CU. grp = blk&7 (dir=grp>>2, btile=grp&3), utile = blk>>3.
// Group of 32 blocks owns a [32b x 512u] recurrence slab. Per-step sync = cumulative
// arrival counter (relaxed agent atomics, proven R3). h published via relaxed agent
// atomic stores (write-through to coherence point) BEFORE arrival; consumed via plain
// first-touch global_load_lds. NO threadfence / cache-maintenance anywhere.
__launch_bounds__(256, 1)
__global__ void lstm_persistent(
    const unsigned short* __restrict__ xs, const unsigned short* __restrict__ Wr,
    const float* __restrict__ bias2, const int* __restrict__ lengths,
    const unsigned short* __restrict__ h0buf, const float* __restrict__ c0,
    unsigned short* __restrict__ hsf, unsigned short* __restrict__ hsb,
    unsigned int* __restrict__ ctrl)
{
    extern __shared__ char smem[];
    unsigned short* Wlds = (unsigned short*)smem;                     // 98304 B
    unsigned short* Abuf = (unsigned short*)(smem + 98304);           // 49152 B
    float* gl = (float*)(smem + 98304 + 49152);                       // 8704 B

    const int blk = blockIdx.x;
    const int grp = blk & 7;
    const int dir = grp >> 2;
    const int btile = grp & 3;
    const int utile = blk >> 3;          // 0..31
    const int bg0 = btile * 32;

    const int tid = threadIdx.x;
    const int w = tid >> 6;
    const int l = tid & 63;
    const int l15 = l & 15, l16 = l >> 4;

    unsigned int* gcnt = ctrl + 64 + grp * 16;   // cumulative arrivals for this group

    unsigned short* hs = dir ? hsb : hsf;
    unsigned int* hs_u32 = (unsigned int*)hs;

    // ---- stage resident W: wave w stages n-subtile w (24 k-subtiles)
    {
        const unsigned short* src0 =
            Wr + ((size_t)(dir * 2048 + utile * 64) + (w * 16 + l15)) * 768 + l16 * 8;
        #pragma unroll
        for (int ks = 0; ks < 24; ks++)
            gll16(src0 + ks * 32, Wlds + (w * 24 + ks) * 512);
    }

    // ---- per-thread pointwise state: thread -> (bl = tid>>3, uu2 = (tid&7)*2), 2 units
    const int bl = tid >> 3;
    const int uu2 = (tid & 7) * 2;
    const int u = utile * 16 + uu2;
    const int len_r = lengths[bg0 + bl];
    float c_reg[2];
    c_reg[0] = c0[((size_t)dir * BB + bg0 + bl) * HID + u];
    c_reg[1] = c0[((size_t)dir * BB + bg0 + bl) * HID + u + 1];
    float bias_r[4][2];
    #pragma unroll
    for (int g = 0; g < 4; g++) {
        bias_r[g][0] = bias2[dir * 2048 + g * 512 + u];
        bias_r[g][1] = bias2[dir * 2048 + g * 512 + u + 1];
    }

    const int m  = w & 1;          // wave's m-subtile
    const int n0 = (w >> 1) * 2;   // wave's first n-subtile (gate pair)

    f32x4 acc0, acc1;
    auto mfma_ks = [&](int ks0, int ks1) {
        #pragma unroll
        for (int ks = ks0; ks < ks1; ks++) {
            short8 a  = *(const short8*)(Abuf + ((m * 24 + ks) << 9) + (l << 3));
            short8 b0 = *(const short8*)(Wlds + ((n0 * 24 + ks) << 9) + (l << 3));
            short8 b1 = *(const short8*)(Wlds + (((n0 + 1) * 24 + ks) << 9) + (l << 3));
            acc0 = __builtin_amdgcn_mfma_f32_16x16x32_bf16(a, b0, acc0, 0, 0, 0);
            acc1 = __builtin_amdgcn_mfma_f32_16x16x32_bf16(a, b1, acc1, 0, 0, 0);
        }
    };

    for (int s = 0; s < TT; s++) {
        const int t = dir ? (TT - 1 - s) : s;

        // ---- stage xs part (ks 0..7): wave w -> (m'=w&1, ks=(w>>1)*4 ..+4)
        {
            int mm = w & 1, ksb = (w >> 1) * 4;
            const unsigned short* asrc =
                xs + ((size_t)t * BB + (bg0 + mm * 16 + l15)) * EMBD + l16 * 8;
            #pragma unroll
            for (int q = 0; q < 4; q++)
                gll16(asrc + (ksb + q) * 32, Abuf + (mm * 24 + ksb + q) * 512);
        }
        __syncthreads();                 // xs staged (W too at s==0)

        acc0 = (f32x4){0.f, 0.f, 0.f, 0.f};
        acc1 = (f32x4){0.f, 0.f, 0.f, 0.f};
        mfma_ks(0, 8);                   // xs contribution overlaps group skew

        // ---- wait for group h(t_prev): cumulative-counter barrier (proven atomics)
        if (s > 0) {
            if (tid == 0) {
                unsigned tgt = GBLK * (unsigned)s;
                while (__hip_atomic_load(gcnt, __ATOMIC_RELAXED,
                                         __HIP_MEMORY_SCOPE_AGENT) < tgt)
                    __builtin_amdgcn_s_sleep(1);
            }
            __syncthreads();
        }
        const unsigned short* hsrc = (s == 0)
            ? (h0buf + (size_t)dir * BB * HID)
            : (hs + (size_t)(dir ? (t + 1) : (t - 1)) * BB * HID);

        // ---- stage h part (ks 8..23): plain first-touch loads
        {
            int mm = w & 1, ksb = 8 + (w >> 1) * 8;
            const unsigned short* asrcH = hsrc + (size_t)(bg0 + mm * 16 + l15) * HID + l16 * 8;
            #pragma unroll
            for (int q = 0; q < 8; q++)
                gll16(asrcH + ((ksb + q) * 32 - 256), Abuf + (mm * 24 + ksb + q) * 512);
        }
        __syncthreads();                 // h staged

        mfma_ks(8, 24);

        // ---- accumulators -> gl (C layout: col = l&15, row = 4*(l>>4)+r ; verified R2)
        {
            int rb = m * 16 + l16 * 4;
            #pragma unroll
            for (int r = 0; r < 4; r++) {
                gl[(rb + r) * 68 + n0 * 16 + l15]       = acc0[r];
                gl[(rb + r) * 68 + (n0 + 1) * 16 + l15] = acc1[r];
            }
        }
        __syncthreads();

        // ---- pointwise LSTM update; publish h via relaxed-agent atomic store
        {
            unsigned short hv[2];
            bool msk = t < len_r;
            if (msk) {
                #pragma unroll
                for (int j = 0; j < 2; j++) {
                    float gi = gl[bl * 68 +      uu2 + j] + bias_r[0][j];
                    float gf = gl[bl * 68 + 16 + uu2 + j] + bias_r[1][j];
                    float gg = gl[bl * 68 + 32 + uu2 + j] + bias_r[2][j];
                    float go = gl[bl * 68 + 48 + uu2 + j] + bias_r[3][j];
                    float cn = sigm(gf) * c_reg[j] + sigm(gi) * tanhf(gg);
                    c_reg[j] = cn;
                    hv[j] = f2bf(sigm(go) * tanhf(cn));
                }
            } else {
                // carried h: read h_prev back out of the staged A fragment (k = 256+u)
                int k = 256 + u;
                int ks = k >> 5, kin = k & 31;
                int base = ((bl >> 4) * 24 + ks) * 512 + ((kin >> 3) * 16 + (bl & 15)) * 8 + (kin & 7);
                hv[0] = Abuf[base];
                hv[1] = Abuf[base + 1];
            }
            unsigned int pk = (unsigned int)hv[0] | ((unsigned int)hv[1] << 16);
            size_t widx = (((size_t)t * BB + (bg0 + bl)) * HID + u) >> 1;
            __hip_atomic_store(hs_u32 + widx, pk, __ATOMIC_RELAXED,
                               __HIP_MEMORY_SCOPE_AGENT);
        }
        __syncthreads();                 // vmcnt(0): all h stores acked at coherence point

        // ---- arrive (relaxed agent RMW; ordering given by the drain above)
        if (tid == 0)
            __hip_atomic_fetch_add(gcnt, 1u, __ATOMIC_RELAXED, __HIP_MEMORY_SCOPE_AGENT);
    }
}

// ---------------- emissions: one wave per (t,b) row ----------------
__global__ void emissions_wave(const unsigned short* __restrict__ hsf,
                               const unsigned short* __restrict__ hsb,
                               const float* __restrict__ fcW, const float* __restrict__ fcb,
                               float* __restrict__ emis)
{
    int wid = (blockIdx.x * blockDim.x + threadIdx.x) >> 6;
    int l = threadIdx.x & 63;
    if (wid >= TT * BB) return;
    uint4 vf = *(const uint4*)(hsf + (size_t)wid * HID + l * 8);
    uint4 vb = *(const uint4*)(hsb + (size_t)wid * HID + l * 8);
    unsigned int uf[4] = {vf.x, vf.y, vf.z, vf.w};
    unsigned int ub[4] = {vb.x, vb.y, vb.z, vb.w};
    float xf[8], xb[8];
    #pragma unroll
    for (int j = 0; j < 4; j++) {
        xf[2*j]   = __uint_as_float(uf[j] << 16);
        xf[2*j+1] = __uint_as_float(uf[j] & 0xffff0000u);
        xb[2*j]   = __uint_as_float(ub[j] << 16);
        xb[2*j+1] = __uint_as_float(ub[j] & 0xffff0000u);
    }
    float acc[KTAG];
    #pragma unroll
    for (int k = 0; k < KTAG; k++) {
        const float* wfp = fcW + k * 1024 + l * 8;
        const float* wbp = fcW + k * 1024 + 512 + l * 8;
        float a = 0.f;
        #pragma unroll
        for (int j = 0; j < 8; j++) a += xf[j] * wfp[j] + xb[j] * wbp[j];
        acc[k] = a;
    }
    #pragma unroll
    for (int k = 0; k < KTAG; k++) {
        #pragma unroll
        for (int off = 32; off >= 1; off >>= 1) acc[k] += __shfl_xor(acc[k], off, 64);
    }
    if (l == 0) {
        float* e = emis + (size_t)wid * KTAG;
        #pragma unroll
        for (int k = 0; k < KTAG; k++) e[k] = acc[k] + fcb[k];
    }
}

// ---------------- CRF log-partition: one wave per batch row ----------------
__global__ void crf_partition_kernel(const float* __restrict__ emis, const int* __restrict__ lengths,
                                     const float* __restrict__ trans, float* __restrict__ logz)
{
    int b = blockIdx.x;
    int lane = threadIdx.x;   // 64
    float trow[KTAG];
    #pragma unroll
    for (int j = 0; j < KTAG; j++)
        trow[j] = (lane < KTAG) ? trans[lane * KTAG + j] : -1e30f;
    float alpha = (lane == START_TAG) ? 0.0f : -10000.0f;
    int len = lengths[b];
    for (int t = 0; t < len; t++) {
        float sc[KTAG];
        #pragma unroll
        for (int j = 0; j < KTAG; j++) {
            float aj = __shfl(alpha, j, 64);
            sc[j] = aj + trow[j];
        }
        float m = sc[0];
        #pragma unroll
        for (int j = 1; j < KTAG; j++) m = fmaxf(m, sc[j]);
        float ssum = 0.0f;
        #pragma unroll
        for (int j = 0; j < KTAG; j++) ssum += expf(sc[j] - m);
        float em = (lane < KTAG) ? emis[((size_t)t * BB + b) * KTAG + lane] : 0.0f;
        float anew = m + logf(ssum) + em;
        alpha = (lane < KTAG) ? anew : alpha;
    }
    float v = (lane < KTAG) ? (alpha + trans[STOP_TAG * KTAG + lane]) : -1e30f;
    float m = v;
    #pragma unroll
    for (int off = 1; off < 16; off <<= 1) m = fmaxf(m, __shfl_xor(m, off, 64));
    float e = expf(v - m);
    #pragma unroll
    for (int off = 1; off < 16; off <<= 1) e += __shfl_xor(e, off, 64);
    if (lane == 0) logz[b] = m + logf(e);
}

// ---------------- gold score + final output ----------------
__global__ void gold_kernel(const float* __restrict__ emis, const int* __restrict__ tags,
                            const int* __restrict__ lengths, const float* __restrict__ trans,
                            const float* __restrict__ logz, float* __restrict__ out)
{
    int b = blockIdx.x * blockDim.x + threadIdx.x;
    if (b >= BB) return;
    int len = lengths[b];
    float score = 0.0f;
    int prev = START_TAG;
    for (int t = 0; t < len; t++) {
        int nxt = tags[b * TT + t];
        score += trans[nxt * KTAG + prev] + emis[((size_t)t * BB + b) * KTAG + nxt];
        prev = nxt;
    }
    score += trans[STOP_TAG * KTAG + prev];
    out[b] = logz[b] - score;
}

extern "C" void kernel_launch(void* const* d_in, const int* in_sizes, int n_in,
                              void* d_out, int out_size, void* d_ws, size_t ws_size,
                              hipStream_t stream)
{
    (void)in_sizes; (void)n_in; (void)out_size; (void)ws_size;
    const int*   x     = (const int*)d_in[0];
    const int*   lens  = (const int*)d_in[1];
    const int*   tags  = (const int*)d_in[2];
    const float* emb   = (const float*)d_in[3];
    const float* Wihf  = (const float*)d_in[4];
    const float* Whhf  = (const float*)d_in[5];
    const float* bihf  = (const float*)d_in[6];
    const float* bhhf  = (const float*)d_in[7];
    const float* Wihb  = (const float*)d_in[8];
    const float* Whhb  = (const float*)d_in[9];
    const float* bihb  = (const float*)d_in[10];
    const float* bhhb  = (const float*)d_in[11];
    const float* fcW   = (const float*)d_in[12];
    const float* fcb   = (const float*)d_in[13];
    const float* trans = (const float*)d_in[14];
    const float* h0    = (const float*)d_in[15];
    const float* c0    = (const float*)d_in[16];
    float* out = (float*)d_out;

    char* ws = (char*)d_ws;
    size_t off = 0;
    auto alloc = [&](size_t bytes) {
        void* p = ws + off;
        off += (bytes + 255) & ~(size_t)255;
        return p;
    };
    unsigned short* xs    = (unsigned short*)alloc((size_t)TT * BB * EMBD * 2);
    unsigned short* Wr    = (unsigned short*)alloc((size_t)2 * 2048 * 768 * 2);
    float*          bias2 = (float*)alloc((size_t)2 * 2048 * 4);
    unsigned short* h0buf = (unsigned short*)alloc((size_t)2 * BB * HID * 2);
    unsigned short* hsf   = (unsigned short*)alloc((size_t)TT * BB * HID * 2);
    unsigned short* hsb   = (unsigned short*)alloc((size_t)TT * BB * HID * 2);
    float*          emis  = (float*)alloc((size_t)TT * BB * KTAG * 4);
    float*          logz  = (float*)alloc((size_t)BB * 4);
    unsigned int*   ctrl  = (unsigned int*)alloc((size_t)512 * 4);

    prep_state<<<512, 256, 0, stream>>>(h0, bihf, bhhf, bihb, bhhb, h0buf, bias2, ctrl);
    xs_gather<<<4096, 256, 0, stream>>>(x, emb, xs);
    w_reorder<<<1536, 256, 0, stream>>>(Wihf, Whhf, Wihb, Whhb, Wr);

    hipFuncSetAttribute(reinterpret_cast<const void*>(lstm_persistent),
                        hipFuncAttributeMaxDynamicSharedMemorySize, SMEM_BYTES);
    {
        const unsigned short* p_xs = xs; const unsigned short* p_Wr = Wr;
        const float* p_bias2 = bias2; const int* p_lens = lens;
        const unsigned short* p_h0 = h0buf; const float* p_c0 = c0;
        unsigned short* p_hsf = hsf; unsigned short* p_hsb = hsb;
        unsigned int* p_ctrl = ctrl;
        void* args[9] = { &p_xs, &p_Wr, &p_bias2, &p_lens, &p_h0, &p_c0,
                          &p_hsf, &p_hsb, &p_ctrl };
        hipError_t e = hipLaunchCooperativeKernel(
            reinterpret_cast<const void*>(lstm_persistent),
            dim3(256), dim3(256), args, (unsigned)SMEM_BYTES, stream);
        if (e != hipSuccess) {
            // fallback: 1 block/CU, grid == CU count -> co-resident in practice
            lstm_persistent<<<256, 256, SMEM_BYTES, stream>>>(
                xs, Wr, bias2, lens, h0buf, c0, hsf, hsb, ctrl);
        }
    }

    emissions_wave<<<8192, 256, 0, stream>>>(hsf, hsb, fcW, fcb, emis);
    crf_partition_kernel<<<BB, 64, 0, stream>>>(emis, lens, trans, logz);
    gold_kernel<<<1, BB, 0, stream>>>(emis, tags, lens, trans, logz, out);
}

// Round 6
// 1109.938 us; speedup vs baseline: 4.1145x; 1.3009x over previous
//
#include <hip/hip_runtime.h>
#include <hip/hip_bf16.h>

#define TT 256
#define BB 128
#define EMBD 256
#define HID 512
#define KTAG 12
#define START_TAG 10
#define STOP_TAG 11
#define SMEM_BYTES 148608 // 96KB W + 48KB A + 1.2KB hrep

typedef __attribute__((ext_vector_type(8))) short short8;
typedef __attribute__((ext_vector_type(4))) float f32x4;

__device__ __forceinline__ unsigned short f2bf(float f) {
    union { float f; unsigned int u; } v; v.f = f;
    unsigned int r = v.u + 0x7fffu + ((v.u >> 16) & 1u);   // RNE
    return (unsigned short)(r >> 16);
}
__device__ __forceinline__ float fsig(float x) {
    return __fdividef(1.0f, 1.0f + __expf(-x));
}
__device__ __forceinline__ float ftanh(float x) {
    return 2.0f * __fdividef(1.0f, 1.0f + __expf(-2.0f * x)) - 1.0f;
}
__device__ __forceinline__ void gll16(const void* g, void* l) {
    __builtin_amdgcn_global_load_lds((const __attribute__((address_space(1))) void*)g,
                                     (__attribute__((address_space(3))) void*)l, 16, 0, 0);
}
__device__ __forceinline__ void pack8(const float* src, unsigned short* dst) {
    float4 v0 = *(const float4*)src;
    float4 v1 = *(const float4*)(src + 4);
    unsigned short tmp[8];
    tmp[0] = f2bf(v0.x); tmp[1] = f2bf(v0.y); tmp[2] = f2bf(v0.z); tmp[3] = f2bf(v0.w);
    tmp[4] = f2bf(v1.x); tmp[5] = f2bf(v1.y); tmp[6] = f2bf(v1.z); tmp[7] = f2bf(v1.w);
    *(uint4*)dst = *(const uint4*)tmp;
}

// ---------------- fused prologue: xs gather | W reorder | state/bias/fcW prep ----------------
// W reorder: block-local row  nr%64 = wm*16 + ul*4 + g  <->  orig row g*512 + utile*16 + wm*4 + ul
__global__ void prologue(const int* __restrict__ x, const float* __restrict__ emb,
                         const float* __restrict__ Wihf, const float* __restrict__ Whhf,
                         const float* __restrict__ Wihb, const float* __restrict__ Whhb,
                         const float* __restrict__ h0,
                         const float* __restrict__ bihf, const float* __restrict__ bhhf,
                         const float* __restrict__ bihb, const float* __restrict__ bhhb,
                         const float* __restrict__ fcW,
                         unsigned short* __restrict__ xs, unsigned short* __restrict__ Wr,
                         unsigned short* __restrict__ h0buf, float* __restrict__ bias2,
                         unsigned short* __restrict__ fcWr, unsigned int* __restrict__ ctrl)
{
    int blk = blockIdx.x;
    int tid = threadIdx.x;
    if (blk < 4096) {                       // ---- xs gather: bf16 xs[T][B][EMBD]
        int i = blk * 256 + tid;            // one 8-elem chunk
        int chk = i & 31;
        int row = i >> 5;                   // t*BB + b
        int b = row & (BB - 1);
        int t = row >> 7;
        pack8(emb + (size_t)x[b * TT + t] * EMBD + chk * 8, xs + (size_t)row * EMBD + chk * 8);
    } else if (blk < 5632) {                // ---- W reorder -> bf16 Wr[2][2048][768]
        int i = (blk - 4096) * 256 + tid;   // 2*2048*96 chunks
        int c8 = i % 96;
        int r2 = i / 96;
        int nr = r2 & 2047;
        int dir = r2 >> 11;
        int utile = nr >> 6;
        int r6 = nr & 63;
        int wm = r6 >> 4;
        int rr = r6 & 15;
        int ul = rr >> 2, g = rr & 3;
        int orow = g * HID + utile * 16 + wm * 4 + ul;
        int k0 = c8 * 8;
        const float* Wih = dir ? Wihb : Wihf;
        const float* Whh = dir ? Whhb : Whhf;
        const float* src = (k0 < EMBD) ? (Wih + (size_t)orow * EMBD + k0)
                                       : (Whh + (size_t)orow * HID + (k0 - EMBD));
        pack8(src, Wr + ((size_t)dir * 2048 + nr) * 768 + k0);
    } else {                                // ---- state / bias / fcWr / ctrl
        int i = (blk - 5632) * 256 + tid;   // 0..131071
        if (i < 2 * BB * HID) h0buf[i] = f2bf(h0[i]);
        if (i < 2 * 2048) {
            int dir = i >> 11, j = i & 2047;
            bias2[i] = dir ? (bihb[j] + bhhb[j]) : (bihf[j] + bhhf[j]);
        }
        if (i < 16 * 1024) {
            int tag = i >> 10, k = i & 1023;
            fcWr[i] = f2bf(tag < KTAG ? fcW[tag * 1024 + k] : 0.0f);
        }
        if (i < 512) ctrl[i] = 0u;
    }
}

// ---------------- persistent BiLSTM ----------------
// 256 blocks x 256 threads, 1 block/CU. grp = blk&7 (dir=grp>>2, btile=grp&3), utile = blk>>3.
// MFMA operand-swapped: A = W rows (gate-interleaved), B = [xs|h] rows -> each thread's
// acc[r] = gate r of unit (utile*16 + w*4 + l16) for batch col l15 -> in-register pointwise.
// Barrier: 32 per-block flags, parallel-lane poll + __all; release via relaxed-agent store
// after syncthreads vmcnt drain (R5-proven model).
__launch_bounds__(256, 1)
__global__ void lstm_persistent(
    const unsigned short* __restrict__ xs, const unsigned short* __restrict__ Wr,
    const float* __restrict__ bias2, const int* __restrict__ lengths,
    const unsigned short* __restrict__ h0buf, const float* __restrict__ c0,
    unsigned short* __restrict__ hsf, unsigned short* __restrict__ hsb,
    unsigned int* __restrict__ ctrl)
{
    extern __shared__ char smem[];
    unsigned short* Wlds = (unsigned short*)smem;                     // 98304 B
    unsigned short* Abuf = (unsigned short*)(smem + 98304);           // 49152 B
    unsigned short* hrep = (unsigned short*)(smem + 147456);          // [32][18] = 1152 B

    const int blk = blockIdx.x;
    const int grp = blk & 7;
    const int dir = grp >> 2;
    const int btile = grp & 3;
    const int utile = blk >> 3;          // 0..31
    const int bg0 = btile * 32;

    const int tid = threadIdx.x;
    const int w = tid >> 6;
    const int l = tid & 63;
    const int l15 = l & 15, l16 = l >> 4;

    unsigned int* gflags = ctrl + 64 + grp * 32;

    unsigned short* hs = dir ? hsb : hsf;
    unsigned int* hs_u32 = (unsigned int*)hs;

    // ---- stage resident W: wave w stages (and consumes) W-subtile w
    {
        const unsigned short* src0 =
            Wr + ((size_t)(dir * 2048 + utile * 64) + (w * 16 + l15)) * 768 + l16 * 8;
        #pragma unroll
        for (int ks = 0; ks < 24; ks++)
            gll16(src0 + ks * 32, Wlds + (w * 24 + ks) * 512);
    }

    // ---- per-thread state: (unit u, batches bA=bg0+l15 and bB=bg0+16+l15)
    const int u = utile * 16 + w * 4 + l16;
    const int bA = bg0 + l15, bB = bg0 + 16 + l15;
    const int lenA = lengths[bA], lenB = lengths[bB];
    float cA = c0[((size_t)dir * BB + bA) * HID + u];
    float cB = c0[((size_t)dir * BB + bB) * HID + u];
    float bias_r[4];
    #pragma unroll
    for (int g = 0; g < 4; g++) bias_r[g] = bias2[dir * 2048 + g * 512 + u];

    for (int s = 0; s < TT; s++) {
        const int t = dir ? (TT - 1 - s) : s;

        // ---- stage xs part (ks 0..7)
        {
            int mm = w & 1, ksb = (w >> 1) * 4;
            const unsigned short* asrc =
                xs + ((size_t)t * BB + (bg0 + mm * 16 + l15)) * EMBD + l16 * 8;
            #pragma unroll
            for (int q = 0; q < 4; q++)
                gll16(asrc + (ksb + q) * 32, Abuf + (mm * 24 + ksb + q) * 512);
        }
        __syncthreads();                 // xs staged (W too at s==0)

        f32x4 aA0 = {0.f,0.f,0.f,0.f}, aA1 = {0.f,0.f,0.f,0.f};
        f32x4 aB0 = {0.f,0.f,0.f,0.f}, aB1 = {0.f,0.f,0.f,0.f};
        auto mstep = [&](int ks, f32x4& xA, f32x4& xB) {
            short8 a  = *(const short8*)(Wlds + ((w * 24 + ks) << 9) + (l << 3));
            short8 b0 = *(const short8*)(Abuf + (ks << 9) + (l << 3));
            short8 b1 = *(const short8*)(Abuf + ((24 + ks) << 9) + (l << 3));
            xA = __builtin_amdgcn_mfma_f32_16x16x32_bf16(a, b0, xA, 0, 0, 0);
            xB = __builtin_amdgcn_mfma_f32_16x16x32_bf16(a, b1, xB, 0, 0, 0);
        };
        #pragma unroll
        for (int ks = 0; ks < 8; ks += 2) { mstep(ks, aA0, aB0); mstep(ks + 1, aA1, aB1); }

        // ---- wait for group h(t_prev): 32 flags, parallel-lane poll (wave 0)
        if (s > 0) {
            if (tid < 64) {
                unsigned tgt = (unsigned)s;
                unsigned fidx = (unsigned)tid & 31u;
                while (true) {
                    unsigned v = __hip_atomic_load(&gflags[fidx], __ATOMIC_RELAXED,
                                                   __HIP_MEMORY_SCOPE_AGENT);
                    if (__all(v >= tgt)) break;
                }
            }
            __syncthreads();
        }
        const unsigned short* hsrc = (s == 0)
            ? (h0buf + (size_t)dir * BB * HID)
            : (hs + (size_t)(dir ? (t + 1) : (t - 1)) * BB * HID);

        // ---- stage h part (ks 8..23)
        {
            int mm = w & 1, ksb = 8 + (w >> 1) * 8;
            const unsigned short* asrcH = hsrc + (size_t)(bg0 + mm * 16 + l15) * HID + l16 * 8;
            #pragma unroll
            for (int q = 0; q < 8; q++)
                gll16(asrcH + ((ksb + q) * 32 - 256), Abuf + (mm * 24 + ksb + q) * 512);
        }
        __syncthreads();                 // h staged

        #pragma unroll
        for (int ks = 8; ks < 24; ks += 2) { mstep(ks, aA0, aB0); mstep(ks + 1, aA1, aB1); }
        f32x4 accA = aA0 + aA1;
        f32x4 accB = aB0 + aB1;

        // ---- in-register pointwise (gate order i,f,g,o = acc[0..3])
        {
            const int ksn = 8 + (u >> 5), kin = u & 31;
            const int baseA = ksn * 512 + ((kin >> 3) * 16 + l15) * 8 + (kin & 7);
            const int baseB = (24 + ksn) * 512 + ((kin >> 3) * 16 + l15) * 8 + (kin & 7);
            float giA = accA[0] + bias_r[0], gfA = accA[1] + bias_r[1];
            float ggA = accA[2] + bias_r[2], goA = accA[3] + bias_r[3];
            float cnA = fsig(gfA) * cA + fsig(giA) * ftanh(ggA);
            float hnA = fsig(goA) * ftanh(cnA);
            float giB = accB[0] + bias_r[0], gfB = accB[1] + bias_r[1];
            float ggB = accB[2] + bias_r[2], goB = accB[3] + bias_r[3];
            float cnB = fsig(gfB) * cB + fsig(giB) * ftanh(ggB);
            float hnB = fsig(goB) * ftanh(cnB);
            bool mA = t < lenA, mB = t < lenB;
            unsigned short hvA = mA ? f2bf(hnA) : Abuf[baseA];  // carried h from staged frag
            unsigned short hvB = mB ? f2bf(hnB) : Abuf[baseB];
            cA = mA ? cnA : cA;
            cB = mB ? cnB : cB;
            hrep[l15 * 18 + w * 4 + l16]        = hvA;
            hrep[(16 + l15) * 18 + w * 4 + l16] = hvB;
        }
        __syncthreads();

        // ---- packed coalesced publish (R5-proven 4B relaxed-agent atomic stores)
        {
            int bl = tid >> 3, up = tid & 7;
            unsigned v0 = hrep[bl * 18 + up * 2];
            unsigned v1 = hrep[bl * 18 + up * 2 + 1];
            unsigned pk = v0 | (v1 << 16);
            size_t widx = (((size_t)t * BB + (bg0 + bl)) * HID + utile * 16 + up * 2) >> 1;
            __hip_atomic_store(hs_u32 + widx, pk, __ATOMIC_RELAXED, __HIP_MEMORY_SCOPE_AGENT);
        }
        __syncthreads();                 // vmcnt drain: all waves' h stores acked

        // ---- release: one flag store per block (no RMW serialization)
        if (tid == 0)
            __hip_atomic_store(&gflags[utile], (unsigned)(s + 1), __ATOMIC_RELAXED,
                               __HIP_MEMORY_SCOPE_AGENT);
    }
}

// ---------------- emissions as skinny MFMA GEMM: [32768 rows x K=1024] @ fcWr^T ----------------
// one wave per 16 rows; A frags straight from global (hsf|hsb), B frags from bf16 fcWr[16][1024].
__global__ void emissions_mfma(const unsigned short* __restrict__ hsf,
                               const unsigned short* __restrict__ hsb,
                               const unsigned short* __restrict__ fcWr,
                               const float* __restrict__ fcb, float* __restrict__ emis)
{
    int wid = (blockIdx.x * blockDim.x + threadIdx.x) >> 6;   // 2048 waves
    int l = threadIdx.x & 63;
    int l15 = l & 15, l16 = l >> 4;
    int rowbase = wid * 16;
    f32x4 acc0 = {0.f,0.f,0.f,0.f}, acc1 = {0.f,0.f,0.f,0.f};
    auto estep = [&](const unsigned short* hsp, int ks, f32x4& acc) {
        short8 av = *(const short8*)(hsp + (size_t)(rowbase + l15) * HID + (ks & 15) * 32 + l16 * 8);
        short8 bv = *(const short8*)(fcWr + l15 * 1024 + ks * 32 + l16 * 8);
        acc = __builtin_amdgcn_mfma_f32_16x16x32_bf16(av, bv, acc, 0, 0, 0);
    };
    #pragma unroll
    for (int ks = 0; ks < 16; ks += 2) { estep(hsf, ks, acc0); estep(hsf, ks + 1, acc1); }
    #pragma unroll
    for (int ks = 16; ks < 32; ks += 2) { estep(hsb, ks, acc0); estep(hsb, ks + 1, acc1); }
    f32x4 acc = acc0 + acc1;
    float bval = fcb[l15 < KTAG ? l15 : 0];
    if (l15 < KTAG) {
        #pragma unroll
        for (int r = 0; r < 4; r++)
            emis[(size_t)(rowbase + 4 * l16 + r) * KTAG + l15] = acc[r] + bval;
    }
}

// ---------------- fused CRF partition (wave 0, emission-prefetch pipeline) + gold (wave 1) ----------------
__global__ void crf_gold(const float* __restrict__ emis, const int* __restrict__ lengths,
                         const int* __restrict__ tags, const float* __restrict__ trans,
                         float* __restrict__ out)
{
    __shared__ float s_logz, s_gold;
    int b = blockIdx.x;
    int tid = threadIdx.x;   // 128
    int len = lengths[b];
    if (tid < 64) {
        int lane = tid;
        float trow[KTAG];
        #pragma unroll
        for (int j = 0; j < KTAG; j++)
            trow[j] = (lane < KTAG) ? trans[lane * KTAG + j] : -1e30f;
        float alpha = (lane == START_TAG) ? 0.0f : -10000.0f;
        float e_cur = (lane < KTAG) ? emis[(size_t)b * KTAG + lane] : 0.0f;
        for (int t = 0; t < len; t++) {
            int tn = (t + 1 < TT) ? t + 1 : t;
            float e_next = (lane < KTAG) ? emis[(size_t)(tn * BB + b) * KTAG + lane] : 0.0f;
            float sc[KTAG];
            #pragma unroll
            for (int j = 0; j < KTAG; j++) sc[j] = __shfl(alpha, j, 64) + trow[j];
            float m = sc[0];
            #pragma unroll
            for (int j = 1; j < KTAG; j++) m = fmaxf(m, sc[j]);
            float ssum = 0.0f;
            #pragma unroll
            for (int j = 0; j < KTAG; j++) ssum += __expf(sc[j] - m);
            float anew = m + __logf(ssum) + e_cur;
            alpha = (lane < KTAG) ? anew : alpha;
            e_cur = e_next;
        }
        float v = (lane < KTAG) ? (alpha + trans[STOP_TAG * KTAG + lane]) : -1e30f;
        float m = v;
        #pragma unroll
        for (int off = 1; off < 16; off <<= 1) m = fmaxf(m, __shfl_xor(m, off, 64));
        float e = __expf(v - m);
        #pragma unroll
        for (int off = 1; off < 16; off <<= 1) e += __shfl_xor(e, off, 64);
        if (lane == 0) s_logz = m + __logf(e);
    } else {
        int l2 = tid - 64;
        float part = 0.0f;
        #pragma unroll
        for (int q = 0; q < 4; q++) {
            int t = l2 + q * 64;
            if (t < len) {
                int nxt = tags[b * TT + t];
                int prev = t ? tags[b * TT + t - 1] : START_TAG;
                part += trans[nxt * KTAG + prev] + emis[(size_t)(t * BB + b) * KTAG + nxt];
            }
        }
        #pragma unroll
        for (int off = 1; off < 64; off <<= 1) part += __shfl_xor(part, off, 64);
        if (l2 == 0) s_gold = part + trans[STOP_TAG * KTAG + tags[b * TT + len - 1]];
    }
    __syncthreads();
    if (tid == 0) out[b] = s_logz - s_gold;
}

extern "C" void kernel_launch(void* const* d_in, const int* in_sizes, int n_in,
                              void* d_out, int out_size, void* d_ws, size_t ws_size,
                              hipStream_t stream)
{
    (void)in_sizes; (void)n_in; (void)out_size; (void)ws_size;
    const int*   x     = (const int*)d_in[0];
    const int*   lens  = (const int*)d_in[1];
    const int*   tags  = (const int*)d_in[2];
    const float* emb   = (const float*)d_in[3];
    const float* Wihf  = (const float*)d_in[4];
    const float* Whhf  = (const float*)d_in[5];
    const float* bihf  = (const float*)d_in[6];
    const float* bhhf  = (const float*)d_in[7];
    const float* Wihb  = (const float*)d_in[8];
    const float* Whhb  = (const float*)d_in[9];
    const float* bihb  = (const float*)d_in[10];
    const float* bhhb  = (const float*)d_in[11];
    const float* fcW   = (const float*)d_in[12];
    const float* fcb   = (const float*)d_in[13];
    const float* trans = (const float*)d_in[14];
    const float* h0    = (const float*)d_in[15];
    const float* c0    = (const float*)d_in[16];
    float* out = (float*)d_out;

    char* ws = (char*)d_ws;
    size_t off = 0;
    auto alloc = [&](size_t bytes) {
        void* p = ws + off;
        off += (bytes + 255) & ~(size_t)255;
        return p;
    };
    unsigned short* xs    = (unsigned short*)alloc((size_t)TT * BB * EMBD * 2);
    unsigned short* Wr    = (unsigned short*)alloc((size_t)2 * 2048 * 768 * 2);
    float*          bias2 = (float*)alloc((size_t)2 * 2048 * 4);
    unsigned short* h0buf = (unsigned short*)alloc((size_t)2 * BB * HID * 2);
    unsigned short* hsf   = (unsigned short*)alloc((size_t)TT * BB * HID * 2);
    unsigned short* hsb   = (unsigned short*)alloc((size_t)TT * BB * HID * 2);
    float*          emis  = (float*)alloc((size_t)TT * BB * KTAG * 4);
    unsigned short* fcWr  = (unsigned short*)alloc((size_t)16 * 1024 * 2);
    unsigned int*   ctrl  = (unsigned int*)alloc((size_t)512 * 4);

    prologue<<<6144, 256, 0, stream>>>(x, emb, Wihf, Whhf, Wihb, Whhb, h0,
                                       bihf, bhhf, bihb, bhhb, fcW,
                                       xs, Wr, h0buf, bias2, fcWr, ctrl);

    hipFuncSetAttribute(reinterpret_cast<const void*>(lstm_persistent),
                        hipFuncAttributeMaxDynamicSharedMemorySize, SMEM_BYTES);
    {
        const unsigned short* p_xs = xs; const unsigned short* p_Wr = Wr;
        const float* p_bias2 = bias2; const int* p_lens = lens;
        const unsigned short* p_h0 = h0buf; const float* p_c0 = c0;
        unsigned short* p_hsf = hsf; unsigned short* p_hsb = hsb;
        unsigned int* p_ctrl = ctrl;
        void* args[9] = { &p_xs, &p_Wr, &p_bias2, &p_lens, &p_h0, &p_c0,
                          &p_hsf, &p_hsb, &p_ctrl };
        hipError_t e = hipLaunchCooperativeKernel(
            reinterpret_cast<const void*>(lstm_persistent),
            dim3(256), dim3(256), args, (unsigned)SMEM_BYTES, stream);
        if (e != hipSuccess) {
            // fallback: 1 block/CU, grid == CU count -> co-resident in practice
            lstm_persistent<<<256, 256, SMEM_BYTES, stream>>>(
                xs, Wr, bias2, lens, h0buf, c0, hsf, hsb, ctrl);
        }
    }

    emissions_mfma<<<512, 256, 0, stream>>>(hsf, hsb, fcWr, fcb, emis);
    crf_gold<<<BB, 128, 0, stream>>>(emis, lens, tags, trans, out);
}